// Round 7
// baseline (485.180 us; speedup 1.0000x reference)
//
#include <hip/hip_runtime.h>
#include <math.h>

// Transformer-XL relative attention, fp16-MFMA, fused-softmax version.
// B=4 N=16 L=1024 D=64. Outputs: out [B,N,L,D] fp32, then weight [B,N,L,L] fp32.
// rel_shift(pos)[i,j] == pos[i, j - i + (L-1)], only j<=i survives the causal mask.
//
// R7: (a) launch_bounds (512,8)->(512,6): the 64-VGPR cap since R2 likely forced
//     scratch spills (v[16] f32 live across exp + 4 A-frags + addressing ~ >64);
//     84-reg cap / 3 blocks/CU trades 32->24 waves (worth ~10us per R2) against
//     spill elimination. (b) K/P converted on the fly from fp32 (L2-hot reads,
//     +8 cvt/tile) -- prep shrinks to V-transpose only, ws round-trip -12MB.
//     (c) revert R6 dead-zone offload (R5 measured faster). Falsified so far:
//     occupancy(R2), store-drain(R3), VALU+L2(R5), store volume(R6).

#define Bq 4
#define Nh 16
#define Lq 1024
#define Dh 64
#define TQ 16     // query rows per block
#define NT 512    // 8 waves
#define LROW 1032 // f16 row stride (2064 B = 516 dw; 516%32=4 -> 2-way banks, free;
                  // 16B-aligned for ds_read_b128)

// LDS-only barrier: wait for this wave's DS ops, then block barrier. Leaves
// global (vmcnt) traffic in flight across the barrier.
#define BAR() asm volatile("s_waitcnt lgkmcnt(0)\n\ts_barrier" ::: "memory")

typedef _Float16 h16;
typedef __attribute__((ext_vector_type(8))) _Float16 f16x8;
typedef __attribute__((ext_vector_type(4))) _Float16 f16x4;
typedef __attribute__((ext_vector_type(4))) float f32x4;

__device__ __forceinline__ f16x8 pack8h(float4 a, float4 b) {
    f16x8 o;
    o[0] = (h16)a.x; o[1] = (h16)a.y; o[2] = (h16)a.z; o[3] = (h16)a.w;
    o[4] = (h16)b.x; o[5] = (h16)b.y; o[6] = (h16)b.z; o[7] = (h16)b.w;
    return o;
}

__device__ __forceinline__ float wave_max(float v) {
    #pragma unroll
    for (int o = 32; o > 0; o >>= 1) v = fmaxf(v, __shfl_xor(v, o));
    return v;
}
__device__ __forceinline__ float wave_sum(float v) {
    #pragma unroll
    for (int o = 32; o > 0; o >>= 1) v += __shfl_xor(v, o);
    return v;
}

// ---------- prep: V [bn][j][d] fp32 -> Vt [bn][d][j] f16 (only remaining prep) ----------
__global__ __launch_bounds__(256) void prep_kernel(
    const float* __restrict__ V, h16* __restrict__ Vt)
{
    __shared__ float t[64][65];
    int b = blockIdx.x;
    int tid = threadIdx.x;
    int bn = b >> 4, jt = b & 15;
    int d = tid & 63, q = tid >> 6;
    const float* vb = V + ((size_t)(bn * Lq + jt * 64)) * Dh;
    #pragma unroll
    for (int r = 0; r < 16; r++) {
        int jl = r * 4 + q;
        t[jl][d] = vb[(size_t)jl * Dh + d];
    }
    __syncthreads();
    int dd = tid >> 2, jb = (tid & 3) << 4;
    f16x8 s0, s1;
    #pragma unroll
    for (int jj = 0; jj < 8; jj++) {
        s0[jj] = (h16)t[jb + jj][dd];
        s1[jj] = (h16)t[jb + 8 + jj][dd];
    }
    h16* drow = Vt + (((size_t)(bn * 64 + dd)) << 10) + (jt << 6) + jb;
    *(f16x8*)drow = s0;
    *(f16x8*)(drow + 8) = s1;
}

// ---------- main ----------
__global__ __launch_bounds__(NT, 6) void relattn_kernel(
    const float* __restrict__ QC, const float* __restrict__ QP,
    const float* __restrict__ K, const float* __restrict__ P,
    const h16* __restrict__ Vtb,
    float* __restrict__ out, float* __restrict__ wout)
{
    __shared__ __align__(16) h16 s_s[TQ][LROW];     // 33024 B, f16 scores then f16 W
    __shared__ __align__(16) float dscr[4][64][4];  // 4096 B, Phase D split-k combine

    const int tid  = threadIdx.x;
    const int w    = tid >> 6, lane = tid & 63;
    const int ln   = lane & 15, quad = lane >> 4;

    // XCD-contiguous remap: 4096 blocks, 8 XCDs -> 512 consecutive work items per
    // XCD (all 64 query-tiles of bn 0..7 on XCD0, etc -> K/Vtb/P stay L2-hot).
    // Within XCD: heaviest tiles (qt large = long causal rows) first -> short tail.
    const int bidx = blockIdx.x;
    const int wg   = ((bidx & 7) << 9) | (bidx >> 3);
    const int bn   = wg >> 6, qt = 63 - (wg & 63);
    const int nh   = bn & 15;
    const int i0   = qt << 4, i1 = i0 + 15;

    // A fragments from fp32 directly: A[m=ln][k=quad*8+j]
    const float* qcrow = QC + (((size_t)(bn << 10) + i0 + ln) << 6) + (quad << 3);
    const float* qprow = QP + (((size_t)(bn << 10) + i0 + ln) << 6) + (quad << 3);
    f16x8 aC0 = pack8h(*(const float4*)qcrow,        *(const float4*)(qcrow + 4));
    f16x8 aC1 = pack8h(*(const float4*)(qcrow + 32), *(const float4*)(qcrow + 36));
    f16x8 aP0 = pack8h(*(const float4*)qprow,        *(const float4*)(qprow + 4));
    f16x8 aP1 = pack8h(*(const float4*)(qprow + 32), *(const float4*)(qprow + 36));

    // -inf fill of the never-written region j in [i1+1, 1024): 4 rows per
    // 128-thread group, f16x8 stores. Makes Phase C maskless (exp(-inf)=0).
    {
        f16x8 nf;
        #pragma unroll
        for (int k = 0; k < 8; k++) nf[k] = (h16)-INFINITY;
        int rr0 = tid >> 7;             // 0..3
        int tt  = tid & 127;            // 0..127
        int col = i0 + 16 + (tt << 3);
        if (col < 1024) {
            #pragma unroll
            for (int r = rr0; r < 16; r += 4)
                *(f16x8*)&s_s[r][col] = nf;
        }
    }

    // ---- Phase A: content scores S = QC . K^T (causal tiles only) ----
    // K read as fp32, converted in-register (L2-hot; no Kb staging).
    // Diagonal tile (c0 == i0) masked to -inf at store: j > i -> -inf.
    const float* kbase = K + (((size_t)(bn << 10)) << 6) + (quad << 3);
    #pragma unroll
    for (int ct = 0; ct < 8; ct++) {
        int c0 = ((ct << 3) + w) << 4;           // interleave tiles across 8 waves
        if (c0 <= i1) {
            const float* kr = kbase + ((size_t)(c0 + ln) << 6);
            f16x8 k0 = pack8h(*(const float4*)kr,        *(const float4*)(kr + 4));
            f16x8 k1 = pack8h(*(const float4*)(kr + 32), *(const float4*)(kr + 36));
            f32x4 acc = {0.f, 0.f, 0.f, 0.f};
            acc = __builtin_amdgcn_mfma_f32_16x16x32_f16(aC0, k0, acc, 0, 0, 0);
            acc = __builtin_amdgcn_mfma_f32_16x16x32_f16(aC1, k1, acc, 0, 0, 0);
            #pragma unroll
            for (int rg = 0; rg < 4; rg++) {      // C: col=ln, row=quad*4+rg
                int row = (quad << 2) + rg;
                float val = (c0 + ln <= i0 + row) ? acc[rg] : -INFINITY;
                s_s[row][c0 + ln] = (h16)val;
            }
        }
    }
    BAR();

    // ---- Phase B: pos scores T = QP . P^T, scatter-add with rel_shift ----
    // P read as fp32, converted in-register (no Pb staging).
    const float* pbase = P + (((size_t)(nh << 10)) << 6) + (quad << 3);
    #pragma unroll
    for (int ct = 0; ct < 8; ct++) {
        int p0 = ((ct << 3) + w) << 4;
        if (p0 + i0 + 30 >= 1023) {              // some j = p+i-1023 >= 0 in tile
            const float* pr = pbase + ((size_t)(p0 + ln) << 6);
            f16x8 b0 = pack8h(*(const float4*)pr,        *(const float4*)(pr + 4));
            f16x8 b1 = pack8h(*(const float4*)(pr + 32), *(const float4*)(pr + 36));
            f32x4 acc = {0.f, 0.f, 0.f, 0.f};
            acc = __builtin_amdgcn_mfma_f32_16x16x32_f16(aP0, b0, acc, 0, 0, 0);
            acc = __builtin_amdgcn_mfma_f32_16x16x32_f16(aP1, b1, acc, 0, 0, 0);
            int p = p0 + ln;
            #pragma unroll
            for (int rg = 0; rg < 4; rg++) {
                int row = (quad << 2) + rg;
                int j = p + i0 + row - 1023;     // j <= i always (p <= 1023)
                if (j >= 0)                      // unique (row,j) per lane: no race
                    s_s[row][j] = (h16)((float)s_s[row][j] + acc[rg]);
            }
        }
    }
    BAR();

    // ---- Phase C: maskless in-register softmax; nt-store W fp32; pack f16 ----
    // Wave w owns rows 2w, 2w+1. Lane owns j = c*256 + lane*4 + e, c=0..3, e=0..3.
    #pragma unroll
    for (int rr = 0; rr < 2; rr++) {
        int r = (w << 1) + rr;
        int i = i0 + r;
        float v[16];
        #pragma unroll
        for (int c = 0; c < 4; c++) {
            f16x4 t = *(f16x4*)&s_s[r][(c << 8) + (lane << 2)];
            v[c * 4 + 0] = (float)t[0]; v[c * 4 + 1] = (float)t[1];
            v[c * 4 + 2] = (float)t[2]; v[c * 4 + 3] = (float)t[3];
        }
        float mx = v[0];
        #pragma unroll
        for (int k = 1; k < 16; k++) mx = fmaxf(mx, v[k]);
        mx = wave_max(mx);                       // real: row always has j=0 live
        float sum = 0.f;
        #pragma unroll
        for (int k = 0; k < 16; k++) {
            float t = __expf((v[k] - mx) * 0.125f);   // exp(-inf)=0: exact mask zeros
            sum += t;
            v[k] = t;
        }
        sum = wave_sum(sum);
        float inv = __builtin_amdgcn_rcpf(sum);
        float* wrow = wout + (((size_t)(bn << 10) + i) << 10);
        #pragma unroll
        for (int c = 0; c < 4; c++) {
            int j = (c << 8) + (lane << 2);
            f32x4 e;
            e[0] = v[c * 4 + 0] * inv; e[1] = v[c * 4 + 1] * inv;
            e[2] = v[c * 4 + 2] * inv; e[3] = v[c * 4 + 3] * inv;
            __builtin_nontemporal_store(e, (f32x4*)&wrow[j]);  // W: write-once, skip L2
            f16x4 hh;
            hh[0] = (h16)e[0]; hh[1] = (h16)e[1]; hh[2] = (h16)e[2]; hh[3] = (h16)e[3];
            *(f16x4*)&s_s[r][j] = hh;            // f16 A-operand for Phase D, in-place
        }
    }
    BAR();

    // ---- Phase D: out = W . V via MFMA, split-k across wave pairs ----
    // Wave (w&3) owns output cols n0..n0+15; half h = w>>2 takes every other k-step.
    f32x4 o = {0.f, 0.f, 0.f, 0.f};
    const int n0 = (w & 3) << 4;
    const int h  = w >> 2;
    const h16* vtb = Vtb + (((size_t)(bn << 6) + n0 + ln) << 10);
    const h16* abase = &s_s[ln][0];
    const int ksteps = (i0 + 16 + 31) >> 5;       // j <= i1 only; rest of W is 0
    for (int ks = h; ks < ksteps; ks += 2) {
        int k0 = (ks << 5) + (quad << 3);
        f16x8 af = *(const f16x8*)(abase + k0);
        f16x8 vb = *(const f16x8*)(vtb + k0);
        o = __builtin_amdgcn_mfma_f32_16x16x32_f16(af, vb, o, 0, 0, 0);
    }
    if (h == 1)
        *(f32x4*)&dscr[w & 3][lane][0] = o;
    BAR();
    if (h == 0) {
        f32x4 o2 = *(f32x4*)&dscr[w][lane][0];
        o[0] += o2[0]; o[1] += o2[1]; o[2] += o2[2]; o[3] += o2[3];
        float* obase = out + (((size_t)(bn << 10) + i0) << 6);
        #pragma unroll
        for (int rg = 0; rg < 4; rg++)
            __builtin_nontemporal_store(
                o[rg], &obase[((size_t)((quad << 2) + rg) << 6) + n0 + ln]);
    }
}

extern "C" void kernel_launch(void* const* d_in, const int* in_sizes, int n_in,
                              void* d_out, int out_size, void* d_ws, size_t ws_size,
                              hipStream_t stream) {
    const float* qc = (const float*)d_in[0];
    const float* qp = (const float*)d_in[1];
    const float* K  = (const float*)d_in[2];
    const float* V  = (const float*)d_in[3];
    const float* P  = (const float*)d_in[4];
    // d_in[5]: causal mask, hardcoded.

    float* out  = (float*)d_out;
    float* wout = out + (size_t)Bq * Nh * Lq * Dh;

    h16* Vtb = (h16*)d_ws;                         // 8 MB of ws

    prep_kernel<<<Bq * Nh * 16, 256, 0, stream>>>(V, Vtb);
    relattn_kernel<<<Bq * Nh * (Lq / TQ), NT, 0, stream>>>(qc, qp, K, P, Vtb, out, wout);
}

// Round 8
// 428.986 us; speedup vs baseline: 1.1310x; 1.1310x over previous
//
#include <hip/hip_runtime.h>
#include <math.h>

// Transformer-XL relative attention, fp16-MFMA, fused-softmax version.
// B=4 N=16 L=1024 D=64. Outputs: out [B,N,L,D] fp32, then weight [B,N,L,L] fp32.
// rel_shift(pos)[i,j] == pos[i, j - i + (L-1)], only j<=i survives the causal mask.
//
// R8: R5 base (staged f16 Kb/Pb, best measured) + explicit depth-2 load
//     pipelining. R7's counters showed VGPR_Count=36 (NO spills): the 64-reg cap
//     since R2 made the compiler serialize each phase loop (load->wait->MFMA
//     per tile, ~250cy L2 latency exposed ~4.5x per phase, barrier-convoyed).
//     (a) (512,6): 85-VGPR cap, 3 blocks/CU -- trade ~10us of TLP for ILP regs.
//     (b) Phases A/B: rotate K/P tile loads one iteration ahead.
//     (c) Phase D: first V loads issued BEFORE Phase C (independent of softmax;
//     lgkm-only BAR leaves them in flight), af/vb rotated depth-2 in the loop.
//     Falsified so far: occupancy(R2), store-drain(R3), VALU+L2(R5), store
//     volume(R6), spills(R7). This round: serialized-load latency chains.

#define Bq 4
#define Nh 16
#define Lq 1024
#define Dh 64
#define TQ 16     // query rows per block
#define NT 512    // 8 waves
#define LROW 1032 // f16 row stride (2064 B = 516 dw; 516%32=4 -> 2-way banks, free;
                  // 16B-aligned for ds_read_b128)

// LDS-only barrier: wait for this wave's DS ops, then block barrier. Leaves
// global (vmcnt) traffic in flight across the barrier.
#define BAR() asm volatile("s_waitcnt lgkmcnt(0)\n\ts_barrier" ::: "memory")

typedef _Float16 h16;
typedef __attribute__((ext_vector_type(8))) _Float16 f16x8;
typedef __attribute__((ext_vector_type(4))) _Float16 f16x4;
typedef __attribute__((ext_vector_type(4))) float f32x4;

__device__ __forceinline__ f16x8 pack8h(float4 a, float4 b) {
    f16x8 o;
    o[0] = (h16)a.x; o[1] = (h16)a.y; o[2] = (h16)a.z; o[3] = (h16)a.w;
    o[4] = (h16)b.x; o[5] = (h16)b.y; o[6] = (h16)b.z; o[7] = (h16)b.w;
    return o;
}

__device__ __forceinline__ float wave_max(float v) {
    #pragma unroll
    for (int o = 32; o > 0; o >>= 1) v = fmaxf(v, __shfl_xor(v, o));
    return v;
}
__device__ __forceinline__ float wave_sum(float v) {
    #pragma unroll
    for (int o = 32; o > 0; o >>= 1) v += __shfl_xor(v, o);
    return v;
}

// ---------- prep (single dispatch): cvt K,P -> f16; transpose V -> Vt f16 ----------
// blocks 0..4095: K cvt; 4096..5119: P cvt; 5120..6143: V transpose.
__global__ __launch_bounds__(256) void prep_kernel(
    const float* __restrict__ K, const float* __restrict__ P,
    const float* __restrict__ V,
    h16* __restrict__ Kb, h16* __restrict__ Pb, h16* __restrict__ Vt)
{
    __shared__ float t[64][65];
    int b = blockIdx.x;
    int tid = threadIdx.x;
    if (b < 5120) {
        const float* src; h16* dst; int idx;
        if (b < 4096) { idx = b * 256 + tid; src = K; dst = Kb; }
        else          { idx = (b - 4096) * 256 + tid; src = P; dst = Pb; }
        float4 v = ((const float4*)src)[idx];
        f16x4 o;
        o[0] = (h16)v.x; o[1] = (h16)v.y; o[2] = (h16)v.z; o[3] = (h16)v.w;
        ((f16x4*)dst)[idx] = o;
        return;
    }
    int bv = b - 5120;
    int bn = bv >> 4, jt = bv & 15;
    int d = tid & 63, q = tid >> 6;
    const float* vb = V + ((size_t)(bn * Lq + jt * 64)) * Dh;
    #pragma unroll
    for (int r = 0; r < 16; r++) {
        int jl = r * 4 + q;
        t[jl][d] = vb[(size_t)jl * Dh + d];
    }
    __syncthreads();
    int dd = tid >> 2, jb = (tid & 3) << 4;
    f16x8 s0, s1;
    #pragma unroll
    for (int jj = 0; jj < 8; jj++) {
        s0[jj] = (h16)t[jb + jj][dd];
        s1[jj] = (h16)t[jb + 8 + jj][dd];
    }
    h16* drow = Vt + (((size_t)(bn * 64 + dd)) << 10) + (jt << 6) + jb;
    *(f16x8*)drow = s0;
    *(f16x8*)(drow + 8) = s1;
}

// ---------- main ----------
__global__ __launch_bounds__(NT, 6) void relattn_kernel(
    const float* __restrict__ QC, const float* __restrict__ QP,
    const h16* __restrict__ Kb, const h16* __restrict__ Pb,
    const h16* __restrict__ Vtb,
    float* __restrict__ out, float* __restrict__ wout)
{
    __shared__ __align__(16) h16 s_s[TQ][LROW];     // 33024 B, f16 scores then f16 W
    __shared__ __align__(16) float dscr[4][64][4];  // 4096 B, Phase D split-k combine

    const int tid  = threadIdx.x;
    const int w    = tid >> 6, lane = tid & 63;
    const int ln   = lane & 15, quad = lane >> 4;

    // XCD-contiguous remap: 4096 blocks, 8 XCDs -> 512 consecutive work items per
    // XCD (all 64 query-tiles of bn 0..7 on XCD0, etc -> Kb/Vtb/Pb stay L2-hot).
    // Within XCD: heaviest tiles (qt large = long causal rows) first -> short tail.
    const int bidx = blockIdx.x;
    const int wg   = ((bidx & 7) << 9) | (bidx >> 3);
    const int bn   = wg >> 6, qt = 63 - (wg & 63);
    const int nh   = bn & 15;
    const int i0   = qt << 4, i1 = i0 + 15;

    // A fragments from fp32 directly: A[m=ln][k=quad*8+j]
    const float* qcrow = QC + (((size_t)(bn << 10) + i0 + ln) << 6) + (quad << 3);
    const float* qprow = QP + (((size_t)(bn << 10) + i0 + ln) << 6) + (quad << 3);
    f16x8 aC0 = pack8h(*(const float4*)qcrow,        *(const float4*)(qcrow + 4));
    f16x8 aC1 = pack8h(*(const float4*)(qcrow + 32), *(const float4*)(qcrow + 36));
    f16x8 aP0 = pack8h(*(const float4*)qprow,        *(const float4*)(qprow + 4));
    f16x8 aP1 = pack8h(*(const float4*)(qprow + 32), *(const float4*)(qprow + 36));

    // -inf fill of the never-written region j in [i1+1, 1024): 4 rows per
    // 128-thread group, f16x8 stores. Makes Phase C maskless (exp(-inf)=0).
    {
        f16x8 nf;
        #pragma unroll
        for (int k = 0; k < 8; k++) nf[k] = (h16)-INFINITY;
        int rr0 = tid >> 7;             // 0..3
        int tt  = tid & 127;            // 0..127
        int col = i0 + 16 + (tt << 3);
        if (col < 1024) {
            #pragma unroll
            for (int r = rr0; r < 16; r += 4)
                *(f16x8*)&s_s[r][col] = nf;
        }
    }

    // ---- Phase A: content scores S = QC . K^T (causal tiles only) ----
    // Depth-2 rotation: tile ct+1's K loads issued before tile ct's MFMA.
    // Tiles are monotone in c0 per wave -> once dead, always dead.
    const h16* kbase = Kb + (((size_t)(bn << 10)) << 6) + (quad << 3);
    {
        f16x8 kc0, kc1, kn0, kn1;
        if ((w << 4) <= i1) {                     // preload ct=0 (c0 = w*16)
            const h16* kr = kbase + ((size_t)((w << 4) + ln) << 6);
            kc0 = *(const f16x8*)kr; kc1 = *(const f16x8*)(kr + 32);
        }
        #pragma unroll
        for (int ct = 0; ct < 8; ct++) {
            int c0 = ((ct << 3) + w) << 4;        // interleave tiles across 8 waves
            if (ct < 7) {
                int c0n = (((ct + 1) << 3) + w) << 4;
                if (c0n <= i1) {
                    const h16* kr = kbase + ((size_t)(c0n + ln) << 6);
                    kn0 = *(const f16x8*)kr; kn1 = *(const f16x8*)(kr + 32);
                }
            }
            if (c0 <= i1) {
                f32x4 acc = {0.f, 0.f, 0.f, 0.f};
                acc = __builtin_amdgcn_mfma_f32_16x16x32_f16(aC0, kc0, acc, 0, 0, 0);
                acc = __builtin_amdgcn_mfma_f32_16x16x32_f16(aC1, kc1, acc, 0, 0, 0);
                #pragma unroll
                for (int rg = 0; rg < 4; rg++) {  // C: col=ln, row=quad*4+rg
                    int row = (quad << 2) + rg;
                    float val = (c0 + ln <= i0 + row) ? acc[rg] : -INFINITY;
                    s_s[row][c0 + ln] = (h16)val;
                }
            }
            kc0 = kn0; kc1 = kn1;
        }
    }
    BAR();

    // ---- Phase B: pos scores T = QP . P^T, scatter-add with rel_shift ----
    // Depth-2 rotation; live condition monotone increasing in ct.
    const h16* pbase = Pb + (((size_t)(nh << 10)) << 6) + (quad << 3);
    {
        f16x8 pc0, pc1, pn0, pn1;
        if ((w << 4) + i0 + 30 >= 1023) {         // preload ct=0 (p0 = w*16)
            const h16* pr = pbase + ((size_t)((w << 4) + ln) << 6);
            pc0 = *(const f16x8*)pr; pc1 = *(const f16x8*)(pr + 32);
        }
        #pragma unroll
        for (int ct = 0; ct < 8; ct++) {
            int p0 = ((ct << 3) + w) << 4;
            if (ct < 7) {
                int p0n = (((ct + 1) << 3) + w) << 4;
                if (p0n + i0 + 30 >= 1023) {
                    const h16* pr = pbase + ((size_t)(p0n + ln) << 6);
                    pn0 = *(const f16x8*)pr; pn1 = *(const f16x8*)(pr + 32);
                }
            }
            if (p0 + i0 + 30 >= 1023) {          // some j = p+i-1023 >= 0 in tile
                f32x4 acc = {0.f, 0.f, 0.f, 0.f};
                acc = __builtin_amdgcn_mfma_f32_16x16x32_f16(aP0, pc0, acc, 0, 0, 0);
                acc = __builtin_amdgcn_mfma_f32_16x16x32_f16(aP1, pc1, acc, 0, 0, 0);
                int p = p0 + ln;
                #pragma unroll
                for (int rg = 0; rg < 4; rg++) {
                    int row = (quad << 2) + rg;
                    int j = p + i0 + row - 1023; // j <= i always (p <= 1023)
                    if (j >= 0)                  // unique (row,j) per lane: no race
                        s_s[row][j] = (h16)((float)s_s[row][j] + acc[rg]);
                }
            }
            pc0 = pn0; pc1 = pn1;
        }
    }
    BAR();

    // Phase D V prefetch: independent of softmax; issued here so ~1k cycles of
    // Phase C hide the global latency. lgkm-only BAR leaves them in flight.
    const int n0 = (w & 3) << 4;
    const int h  = w >> 2;
    const h16* vtb = Vtb + (((size_t)(bn << 6) + n0 + ln) << 10);
    f16x8 vb0 = *(const f16x8*)(vtb + ((h    ) << 5) + (quad << 3));
    f16x8 vb1 = *(const f16x8*)(vtb + ((h + 2) << 5) + (quad << 3));

    // ---- Phase C: maskless in-register softmax; nt-store W fp32; pack f16 ----
    // Wave w owns rows 2w, 2w+1. Lane owns j = c*256 + lane*4 + e, c=0..3, e=0..3.
    #pragma unroll
    for (int rr = 0; rr < 2; rr++) {
        int r = (w << 1) + rr;
        int i = i0 + r;
        float v[16];
        #pragma unroll
        for (int c = 0; c < 4; c++) {
            f16x4 t = *(f16x4*)&s_s[r][(c << 8) + (lane << 2)];
            v[c * 4 + 0] = (float)t[0]; v[c * 4 + 1] = (float)t[1];
            v[c * 4 + 2] = (float)t[2]; v[c * 4 + 3] = (float)t[3];
        }
        float mx = v[0];
        #pragma unroll
        for (int k = 1; k < 16; k++) mx = fmaxf(mx, v[k]);
        mx = wave_max(mx);                       // real: row always has j=0 live
        float sum = 0.f;
        #pragma unroll
        for (int k = 0; k < 16; k++) {
            float t = __expf((v[k] - mx) * 0.125f);   // exp(-inf)=0: exact mask zeros
            sum += t;
            v[k] = t;
        }
        sum = wave_sum(sum);
        float inv = __builtin_amdgcn_rcpf(sum);
        float* wrow = wout + (((size_t)(bn << 10) + i) << 10);
        #pragma unroll
        for (int c = 0; c < 4; c++) {
            int j = (c << 8) + (lane << 2);
            f32x4 e;
            e[0] = v[c * 4 + 0] * inv; e[1] = v[c * 4 + 1] * inv;
            e[2] = v[c * 4 + 2] * inv; e[3] = v[c * 4 + 3] * inv;
            __builtin_nontemporal_store(e, (f32x4*)&wrow[j]);  // W: write-once, skip L2
            f16x4 hh;
            hh[0] = (h16)e[0]; hh[1] = (h16)e[1]; hh[2] = (h16)e[2]; hh[3] = (h16)e[3];
            *(f16x4*)&s_s[r][j] = hh;            // f16 A-operand for Phase D, in-place
        }
    }
    BAR();

    // ---- Phase D: out = W . V via MFMA, split-k across wave pairs ----
    // Wave (w&3) owns output cols n0..n0+15; half h = w>>2 takes every other k-step.
    // af (LDS) and vb (global) both rotated depth-2.
    f32x4 o = {0.f, 0.f, 0.f, 0.f};
    const h16* abase = &s_s[ln][0];
    const int ksteps = (i0 + 16 + 31) >> 5;       // j <= i1 only; rest of W is 0
    f16x8 af = *(const f16x8*)(abase + (h << 5) + (quad << 3));
    for (int ks = h; ks < ksteps; ks += 2) {
        f16x8 afn = {}, vnn = {};
        if (ks + 2 < ksteps)
            afn = *(const f16x8*)(abase + ((ks + 2) << 5) + (quad << 3));
        if (ks + 4 < ksteps)
            vnn = *(const f16x8*)(vtb + ((ks + 4) << 5) + (quad << 3));
        o = __builtin_amdgcn_mfma_f32_16x16x32_f16(af, vb0, o, 0, 0, 0);
        af = afn; vb0 = vb1; vb1 = vnn;
    }
    if (h == 1)
        *(f32x4*)&dscr[w & 3][lane][0] = o;
    BAR();
    if (h == 0) {
        f32x4 o2 = *(f32x4*)&dscr[w][lane][0];
        o[0] += o2[0]; o[1] += o2[1]; o[2] += o2[2]; o[3] += o2[3];
        float* obase = out + (((size_t)(bn << 10) + i0) << 6);
        #pragma unroll
        for (int rg = 0; rg < 4; rg++)
            __builtin_nontemporal_store(
                o[rg], &obase[((size_t)((quad << 2) + rg) << 6) + n0 + ln]);
    }
}

extern "C" void kernel_launch(void* const* d_in, const int* in_sizes, int n_in,
                              void* d_out, int out_size, void* d_ws, size_t ws_size,
                              hipStream_t stream) {
    const float* qc = (const float*)d_in[0];
    const float* qp = (const float*)d_in[1];
    const float* K  = (const float*)d_in[2];
    const float* V  = (const float*)d_in[3];
    const float* P  = (const float*)d_in[4];
    // d_in[5]: causal mask, hardcoded.

    float* out  = (float*)d_out;
    float* wout = out + (size_t)Bq * Nh * Lq * Dh;

    const size_t NQ = (size_t)Bq * Nh * Lq * Dh;   // 4,194,304
    const size_t NP = (size_t)Nh * Lq * Dh;        // 1,048,576
    h16* Kb  = (h16*)d_ws;
    h16* Pb  = Kb + NQ;
    h16* Vtb = Pb + NP;                            // total 18 MB of ws

    prep_kernel<<<4096 + 1024 + 1024, 256, 0, stream>>>(K, P, V, Kb, Pb, Vtb);
    relattn_kernel<<<Bq * Nh * (Lq / TQ), NT, 0, stream>>>(qc, qp, Kb, Pb, Vtb, out, wout);
}